// Round 2
// baseline (69.671 us; speedup 1.0000x reference)
//
#include <hip/hip_runtime.h>

#define N_NEUR 4096
#define T_STEPS 2048
#define DT 0.001f
#define TAU 10.0f
#define V_TH 100.0f
#define V_R -100.0f
#define DECAY (1.0f - DT / TAU)   // 0.9999f

#define TR 64                     // tile rows (time steps per LDS tile)
#define NT (T_STEPS / TR)         // 32 tiles
#define NSCAN 64                  // scan blocks (64 neurons each)

// ---------------------------------------------------------------------------
// Fused kernel.
//  blocks 0..63        : speculative u-scan, 64 neurons/block, LDS dbuf staging.
//                        Writes d_ws[b] = 1 if any u ever exceeds 50 (conservative
//                        margin below v_th=100 so fp reassociation can't flip the
//                        decision), else 0. Plain per-block store -> no init kernel.
//  blocks 64..64+2047  : writer for out row t = b-64: s0 * DECAY^(t+1)
//                        (exact no-spike solution; k_slow overwrites if spikes).
// ---------------------------------------------------------------------------
__global__ __launch_bounds__(256) void k_fused(const float* __restrict__ x,
                                               const float* __restrict__ u0,
                                               const float* __restrict__ s0,
                                               float* __restrict__ out,
                                               int* __restrict__ flags) {
    const int b = (int)blockIdx.x;
    const int tid = (int)threadIdx.x;

    if (b >= NSCAN) {
        // ---- writer: one output row per block, 16 KB coalesced float4 ----
        const int t = b - NSCAN;
        const float scale = __powf(DECAY, (float)(t + 1));
        const float4* s4 = (const float4*)s0;
        float4* o4 = (float4*)out + (size_t)t * (N_NEUR / 4);
        #pragma unroll
        for (int p = 0; p < 4; ++p) {
            const int c = p * 256 + tid;
            float4 v = s4[c];
            v.x *= scale; v.y *= scale; v.z *= scale; v.w *= scale;
            o4[c] = v;
        }
        return;
    }

    // ---- scan block b: neurons [b*64, b*64+64) ----
    __shared__ __align__(16) float buf[2][TR][64];   // 32 KB double buffer

    const int lrow = tid >> 4;          // 0..15 : row within a 16-row pass
    const int lq   = tid & 15;          // float4 column quad within the row
    const float4* x4 = (const float4*)x;
    const size_t rowstride4 = N_NEUR / 4;           // 1024
    const size_t cbase4 = (size_t)b * 16 + lq;      // column offset in float4

    float4 r[4];                        // in-flight tile (regs)
    auto issue = [&](int tk) {
        const size_t t0 = (size_t)tk * TR;
        #pragma unroll
        for (int p = 0; p < 4; ++p)
            r[p] = x4[(t0 + (size_t)(p * 16 + lrow)) * rowstride4 + cbase4];
    };
    auto commit = [&](int pb) {
        #pragma unroll
        for (int p = 0; p < 4; ++p)
            *(float4*)&buf[pb][p * 16 + lrow][lq * 4] = r[p];
    };

    // prologue: tile0 -> buf0; tile1 in flight
    issue(0);
    commit(0);
    issue(1);
    __syncthreads();

    const bool scanner = (tid < 64);    // wave 0 runs the sequential chain
    float uu = 0.f, ss = 0.f, um = 0.f;
    if (scanner) {
        uu = u0[b * 64 + tid];
        ss = s0[b * 64 + tid];
        um = uu;                         // u_t checked BEFORE each update
    }

    for (int k = 0; k < NT; ++k) {
        if (scanner) {
            #pragma unroll
            for (int rr = 0; rr < TR; ++rr) {
                const float a = buf[k & 1][rr][tid];
                um = fmaxf(um, uu);
                uu = fmaf(DT, fmaf(uu, uu, a + ss), uu);
                ss *= DECAY;             // s_i(t) = s0_i * DECAY^t while no spikes
            }
        }
        __syncthreads();                 // everyone done with buf[k&1]
        if (k + 1 < NT) commit((k + 1) & 1);   // r holds tile k+1
        if (k + 2 < NT) issue(k + 2);          // next tile into flight
        __syncthreads();                 // buf[(k+1)&1] visible
    }

    if (scanner) {
        const unsigned long long any = __ballot(um >= 50.0f);
        if (tid == 0) flags[b] = (any != 0ull) ? 1 : 0;
    }
}

// ---------------------------------------------------------------------------
// Exact sequential fallback (single block). Runs only if some scan block
// flagged a (potential) spike; overwrites the whole output. Event-driven
// sparse matvec via spike list.
// ---------------------------------------------------------------------------
__global__ __launch_bounds__(1024) void k_slow(const float* __restrict__ x,
                                               const float* __restrict__ W,
                                               const float* __restrict__ u0,
                                               const float* __restrict__ s0,
                                               float* __restrict__ out,
                                               const int* __restrict__ flags) {
    __shared__ int any;
    const int tid = (int)threadIdx.x;
    if (tid == 0) any = 0;
    __syncthreads();
    if (tid < NSCAN && flags[tid] != 0) any = 1;
    __syncthreads();
    if (any == 0) return;                // expected path: immediate exit

    __shared__ float u[N_NEUR];
    __shared__ float s[N_NEUR];
    __shared__ int list[N_NEUR];
    __shared__ int cnt;
    for (int m = tid; m < N_NEUR; m += 1024) { u[m] = u0[m]; s[m] = s0[m]; }
    if (tid == 0) cnt = 0;
    __syncthreads();
    for (int t = 0; t < T_STEPS; ++t) {
        #pragma unroll
        for (int q = 0; q < 4; ++q) {
            const int i = tid + q * 1024;
            const float ui = u[i];
            const bool spk = ui >= V_TH;
            float un = ui + DT * (ui * ui + x[(size_t)t * N_NEUR + i] + s[i]);
            if (spk) {
                int p = atomicAdd(&cnt, 1);
                list[p] = i;
                un = V_R;
            }
            u[i] = un;
        }
        __syncthreads();
        const int k = cnt;
        #pragma unroll
        for (int q = 0; q < 4; ++q) {
            const int i = tid + q * 1024;
            float acc = 0.f;
            for (int m = 0; m < k; ++m) acc += W[(size_t)i * N_NEUR + list[m]];
            const float sn = s[i] * DECAY + acc;
            s[i] = sn;
            out[(size_t)t * N_NEUR + i] = sn;
        }
        __syncthreads();
        if (tid == 0) cnt = 0;
        __syncthreads();
    }
}

// ---------------------------------------------------------------------------
extern "C" void kernel_launch(void* const* d_in, const int* in_sizes, int n_in,
                              void* d_out, int out_size, void* d_ws, size_t ws_size,
                              hipStream_t stream) {
    const float* x  = (const float*)d_in[0];   // [T, N]
    const float* W  = (const float*)d_in[1];   // [N, N]
    const float* u0 = (const float*)d_in[2];   // [N]
    const float* s0 = (const float*)d_in[3];   // [N]
    float* out = (float*)d_out;                // [T, N]
    int* flags = (int*)d_ws;                   // 64 per-block spike flags

    k_fused<<<NSCAN + T_STEPS, 256, 0, stream>>>(x, u0, s0, out, flags);
    k_slow<<<1, 1024, 0, stream>>>(x, W, u0, s0, out, flags);
}

// Round 3
// 45.422 us; speedup vs baseline: 1.5339x; 1.5339x over previous
//
#include <hip/hip_runtime.h>

#define N_NEUR 4096
#define T_STEPS 2048
#define DT 0.001f
#define TAU 10.0f
#define V_TH 100.0f
#define V_R -100.0f
#define DECAY (1.0f - DT / TAU)   // 0.9999f

#define NSCAN 64                  // scan blocks (64 neurons each, 1 wave)
#define CH 64                     // time steps per register chunk
#define NCH (T_STEPS / CH)        // 32 chunks

// ---------------------------------------------------------------------------
// Fused kernel, 64-thread blocks.
//  blocks 0..63      : speculative per-neuron u-scan. Thread = neuron.
//                      Triple-buffered 64-deep REGISTER prefetch (A/B/C),
//                      __launch_bounds__(64,1) so the register minimizer
//                      cannot fold the buffers (round-1 failure mode).
//                      Valid while no spike occurs anywhere; detects any
//                      u >= 50 (conservative margin below v_th=100) and
//                      writes flags[b].
//  blocks 64..64+2047: writer, one output row t=b-64: s0*DECAY^(t+1)
//                      (exact no-spike solution; k_slow overwrites if spikes).
// ---------------------------------------------------------------------------
__global__ __launch_bounds__(64, 1) void k_fused(const float* __restrict__ x,
                                                 const float* __restrict__ u0,
                                                 const float* __restrict__ s0,
                                                 float* __restrict__ out,
                                                 int* __restrict__ flags) {
    const int b = (int)blockIdx.x;
    const int tid = (int)threadIdx.x;

    if (b >= NSCAN) {
        // ---- writer: one row per block, 16 coalesced 1-KB float4 bursts ----
        const int t = b - NSCAN;
        const float scale = __powf(DECAY, (float)(t + 1));
        const float4* s4 = (const float4*)s0;
        float4* o4 = (float4*)out + (size_t)t * (N_NEUR / 4);
        #pragma unroll
        for (int p = 0; p < 16; ++p) {
            const int c = p * 64 + tid;
            float4 v = s4[c];
            v.x *= scale; v.y *= scale; v.z *= scale; v.w *= scale;
            o4[c] = v;
        }
        return;
    }

    // ---- scan block b: neuron i = b*64 + tid ----
    const int i = b * 64 + tid;
    const float* xp = x + i;

    float uu = u0[i];
    float ss = s0[i];
    float um = uu;                       // u_t is checked BEFORE each update

    float A[CH], B[CH], C[CH];

    auto loadch = [&](float (&dst)[CH], int ck) {
        const float* p = xp + (size_t)ck * CH * N_NEUR;
        #pragma unroll
        for (int k = 0; k < CH; ++k) dst[k] = p[(size_t)k * N_NEUR];
    };
    auto compch = [&](const float (&src)[CH]) {
        #pragma unroll
        for (int k = 0; k < CH; ++k) {
            um = fmaxf(um, uu);
            uu = fmaf(DT, fmaf(uu, uu, src[k] + ss), uu);
            ss *= DECAY;                 // s_i(t) = s0_i*DECAY^t while no spikes
        }
    };

    loadch(A, 0);
    loadch(B, 1);
    #pragma unroll 1
    for (int c = 0; c < NCH - 2; c += 3) {   // c = 0,3,...,27
        loadch(C, c + 2); compch(A);
        loadch(A, c + 3); compch(B);
        loadch(B, c + 4); compch(C);
    }
    compch(A);                            // chunk 30
    compch(B);                            // chunk 31

    const unsigned long long any = __ballot(um >= 50.0f);
    if (tid == 0) flags[b] = (any != 0ull) ? 1 : 0;
}

// ---------------------------------------------------------------------------
// Exact sequential fallback (single block). Runs only if some scan block
// flagged a (potential) spike; overwrites the whole output. Event-driven
// sparse matvec via spike list.
// ---------------------------------------------------------------------------
__global__ __launch_bounds__(1024) void k_slow(const float* __restrict__ x,
                                               const float* __restrict__ W,
                                               const float* __restrict__ u0,
                                               const float* __restrict__ s0,
                                               float* __restrict__ out,
                                               const int* __restrict__ flags) {
    __shared__ int any;
    const int tid = (int)threadIdx.x;
    if (tid == 0) any = 0;
    __syncthreads();
    if (tid < NSCAN && flags[tid] != 0) any = 1;
    __syncthreads();
    if (any == 0) return;                // expected path: immediate exit

    __shared__ float u[N_NEUR];
    __shared__ float s[N_NEUR];
    __shared__ int list[N_NEUR];
    __shared__ int cnt;
    for (int m = tid; m < N_NEUR; m += 1024) { u[m] = u0[m]; s[m] = s0[m]; }
    if (tid == 0) cnt = 0;
    __syncthreads();
    for (int t = 0; t < T_STEPS; ++t) {
        #pragma unroll
        for (int q = 0; q < 4; ++q) {
            const int i = tid + q * 1024;
            const float ui = u[i];
            const bool spk = ui >= V_TH;
            float un = ui + DT * (ui * ui + x[(size_t)t * N_NEUR + i] + s[i]);
            if (spk) {
                int p = atomicAdd(&cnt, 1);
                list[p] = i;
                un = V_R;
            }
            u[i] = un;
        }
        __syncthreads();
        const int k = cnt;
        #pragma unroll
        for (int q = 0; q < 4; ++q) {
            const int i = tid + q * 1024;
            float acc = 0.f;
            for (int m = 0; m < k; ++m) acc += W[(size_t)i * N_NEUR + list[m]];
            const float sn = s[i] * DECAY + acc;
            s[i] = sn;
            out[(size_t)t * N_NEUR + i] = sn;
        }
        __syncthreads();
        if (tid == 0) cnt = 0;
        __syncthreads();
    }
}

// ---------------------------------------------------------------------------
extern "C" void kernel_launch(void* const* d_in, const int* in_sizes, int n_in,
                              void* d_out, int out_size, void* d_ws, size_t ws_size,
                              hipStream_t stream) {
    const float* x  = (const float*)d_in[0];   // [T, N]
    const float* W  = (const float*)d_in[1];   // [N, N]
    const float* u0 = (const float*)d_in[2];   // [N]
    const float* s0 = (const float*)d_in[3];   // [N]
    float* out = (float*)d_out;                // [T, N]
    int* flags = (int*)d_ws;                   // 64 per-block spike flags

    k_fused<<<NSCAN + T_STEPS, 64, 0, stream>>>(x, u0, s0, out, flags);
    k_slow<<<1, 1024, 0, stream>>>(x, W, u0, s0, out, flags);
}